// Round 4
// baseline (1493.698 us; speedup 1.0000x reference)
//
#include <hip/hip_runtime.h>

#define N_NODES 50000
#define N_EDGES 400000
#define EMB 32
#define NREL 8
#define NLAYER 5
#define NPB 8           // nodes per block (half-wave each)
#define NROWS 42        // 0..31 P, 32 Stot, 33..40 S_r, 41 hid-stage / h_dst

// ---------------- setup kernels ----------------

__global__ __launch_bounds__(256) void zero_kernel(int* __restrict__ p, int n) {
    int i = blockIdx.x * 256 + threadIdx.x;
    if (i < n) p[i] = 0;
}

__global__ __launch_bounds__(256) void hist_kernel(const int* __restrict__ ei,
                                                   const int* __restrict__ et,
                                                   int* __restrict__ deg,
                                                   int* __restrict__ relcnt) {
    int e = blockIdx.x * 256 + threadIdx.x;
    if (e < N_EDGES) {
        int d = ei[N_EDGES + e];           // dst = edge_index[1]
        atomicAdd(&deg[d], 1);
        atomicAdd(&relcnt[d * NREL + et[e]], 1);
    }
}

__global__ __launch_bounds__(1024) void scan_kernel(const int* __restrict__ deg,
                                                    int* __restrict__ row_ptr) {
    __shared__ int wtot[16];
    __shared__ int pwt[16];
    __shared__ int carry_s;
    int tid = threadIdx.x;
    int lane = tid & 63;
    int w = tid >> 6;
    if (tid == 0) carry_s = 0;
    __syncthreads();
    for (int base = 0; base < N_NODES; base += 1024) {
        int i = base + tid;
        int v = (i < N_NODES) ? deg[i] : 0;
        int incl = v;
        #pragma unroll
        for (int off = 1; off < 64; off <<= 1) {
            int t = __shfl_up(incl, off, 64);
            if (lane >= off) incl += t;
        }
        if (lane == 63) wtot[w] = incl;
        __syncthreads();
        if (tid == 0) {
            int c = carry_s, run = 0;
            #pragma unroll
            for (int j = 0; j < 16; j++) { pwt[j] = c + run; run += wtot[j]; }
            carry_s = c + run;
        }
        __syncthreads();
        if (i < N_NODES) row_ptr[i] = pwt[w] + incl - v;
        __syncthreads();
    }
    if (tid == 0) row_ptr[N_NODES] = carry_s;
}

__global__ __launch_bounds__(256) void inv_kernel(const int* __restrict__ deg,
                                                  const int* __restrict__ relcnt,
                                                  float* __restrict__ invdeg,
                                                  float* __restrict__ invcnt) {
    int n = blockIdx.x * 256 + threadIdx.x;
    if (n < N_NODES) {
        int d = deg[n];
        invdeg[n] = 1.0f / (float)(d > 0 ? d : 1);
        #pragma unroll
        for (int r = 0; r < NREL; r++) {
            int c = relcnt[n * NREL + r];
            invcnt[n * NREL + r] = 1.0f / (float)(c > 0 ? c : 1);
        }
    }
}

__global__ __launch_bounds__(256) void scatter_kernel(const int* __restrict__ ei,
                                                      const int* __restrict__ et,
                                                      const float* __restrict__ ed,
                                                      const int* __restrict__ row_ptr,
                                                      int* __restrict__ cursor,
                                                      int2* __restrict__ edge2) {
    int e = blockIdx.x * 256 + threadIdx.x;
    if (e < N_EDGES) {
        int d = ei[N_EDGES + e];
        int pos = row_ptr[d] + atomicAdd(&cursor[d], 1);
        edge2[pos] = make_int2(ei[e] | (et[e] << 16), __float_as_int(ed[e]));
    }
}

// hid table: hidT[pos][k] = relu(dist*W1[0,k] + W1[1+r,k] + b1[k])  (layer-invariant)
__global__ __launch_bounds__(256) void hid_kernel(const int2* __restrict__ edge2,
                                                  const float* __restrict__ W1,
                                                  const float* __restrict__ b1,
                                                  float* __restrict__ hidT) {
    int tid = threadIdx.x;
    int hw = tid >> 5, lane = tid & 31;
    int pos = blockIdx.x * 8 + hw;
    if (pos < N_EDGES) {
        int2 e = edge2[pos];
        int r = (e.x >> 16) & 7;
        float dist = __int_as_float(e.y);
        float hid = fmaxf(fmaf(dist, W1[lane], W1[(1 + r) * EMB + lane] + b1[lane]), 0.0f);
        hidT[(size_t)pos * EMB + lane] = hid;
    }
}

// transpose contraction weights: WT[m][o*32+i] = src_m[i*32+o]
// m 0..31: W2 rows; m 32: b2; m 33+l*10+j: j<8 rgcnW[l][j], j==8 rgcnRoot[l], j==9 nnRoot[l]
__global__ __launch_bounds__(256) void wt_kernel(const float* __restrict__ W2,
                                                 const float* __restrict__ b2,
                                                 const float* __restrict__ rgcnW,
                                                 const float* __restrict__ rgcnRoot,
                                                 const float* __restrict__ nnRoot,
                                                 float* __restrict__ WT) {
    int m = blockIdx.x;
    const float* src;
    if (m < 32) src = W2 + (size_t)m * 1024;
    else if (m == 32) src = b2;
    else {
        int t = m - 33, l = t / 10, j = t % 10;
        src = (j < 8) ? rgcnW + (size_t)(l * 8 + j) * 1024
            : (j == 8) ? rgcnRoot + (size_t)l * 1024
                       : nnRoot + (size_t)l * 1024;
    }
    float* dst = WT + (size_t)m * 1024;
    #pragma unroll
    for (int c = 0; c < 4; c++) {
        int idx = c * 256 + threadIdx.x;
        int o = idx >> 5, i = idx & 31;
        dst[o * 32 + i] = src[i * 32 + o];
    }
}

// ---------------- fc: h0 = relu(x @ fc_W + fc_b) ----------------

__global__ __launch_bounds__(256) void fc_kernel(const float* __restrict__ x,
                                                 const float* __restrict__ W,
                                                 const float* __restrict__ b,
                                                 float* __restrict__ h) {
    __shared__ __align__(16) float xt[8][EMB];
    int tid = threadIdx.x;
    int nl = tid >> 5, lane = tid & 31;
    int n0 = blockIdx.x * 8;
    xt[tid >> 5][tid & 31] = x[n0 * EMB + tid];
    __syncthreads();
    float acc = b[lane];
    #pragma unroll
    for (int i = 0; i < EMB; i++) acc += xt[nl][i] * W[i * EMB + lane];
    h[(n0 + nl) * EMB + lane] = fmaxf(acc, 0.0f);
}

// ---------------- fused layer kernel ----------------
__global__ __launch_bounds__(256, 3) void layer_kernel(
    const float* __restrict__ h,
    const int2* __restrict__ edge2,
    const int* __restrict__ row_ptr,
    const float* __restrict__ invdeg,
    const float* __restrict__ invcnt,
    const float* __restrict__ hidT,      // may be null (fallback)
    const float* __restrict__ W1,
    const float* __restrict__ b1,
    const float* __restrict__ WTs,       // transposed W2/b2 (rows 0..32)
    const float* __restrict__ WTl,       // transposed per-layer: rgcnW 0..7, rgcnRoot 8, nnRoot 9
    const float* __restrict__ rgcnBias_l,
    const float* __restrict__ nnBias_l,
    int use_hid,
    float* __restrict__ hout)
{
    __shared__ __align__(16) float Prows[NPB][NROWS][EMB];   // 43008 B -> 3 blocks/CU

    const int tid = threadIdx.x;
    const int hw = tid >> 5, lane = tid & 31;
    const int n = blockIdx.x * NPB + hw;   // N divisible by 8: no guard

    // ---------- edge phase ----------
    float P[32];
    #pragma unroll
    for (int k = 0; k < 32; k++) P[k] = 0.0f;
    float stot = 0.0f;

    // zero S_r accumulator rows (lane-private addresses, accumulated via ds_add)
    #pragma unroll
    for (int r = 0; r < NREL; r++) Prows[hw][33 + r][lane] = 0.0f;

    const int pb = row_ptr[n], pe = row_ptr[n + 1];

    if (use_hid) {
        if (pb < pe) {
            int2 e0 = edge2[pb];
            int2 e1 = (pb + 1 < pe) ? edge2[pb + 1] : e0;
            float hv0 = h[(e0.x & 0xFFFF) * EMB + lane];
            float4 hc[8];
            {
                const float4* hp = (const float4*)(hidT + (size_t)pb * EMB);
                #pragma unroll
                for (int jj = 0; jj < 8; jj++) hc[jj] = hp[jj];
            }
            for (int p = pb; p < pe; p++) {
                int p1 = (p + 1 < pe) ? p + 1 : pe - 1;
                int p2 = (p + 2 < pe) ? p + 2 : pe - 1;
                int2 e2 = edge2[p2];                              // 2-deep prefetch
                float hv1 = h[(e1.x & 0xFFFF) * EMB + lane];      // 1-deep gather
                float4 hn[8];
                {
                    const float4* hp = (const float4*)(hidT + (size_t)p1 * EMB);
                    #pragma unroll
                    for (int jj = 0; jj < 8; jj++) hn[jj] = hp[jj];
                }
                int r0 = (e0.x >> 16) & 7;
                atomicAdd(&Prows[hw][33 + r0][lane], hv0);        // ds_add_f32, no-return
                stot += hv0;
                #pragma unroll
                for (int jj = 0; jj < 8; jj++) {
                    P[4 * jj + 0] = fmaf(hc[jj].x, hv0, P[4 * jj + 0]);
                    P[4 * jj + 1] = fmaf(hc[jj].y, hv0, P[4 * jj + 1]);
                    P[4 * jj + 2] = fmaf(hc[jj].z, hv0, P[4 * jj + 2]);
                    P[4 * jj + 3] = fmaf(hc[jj].w, hv0, P[4 * jj + 3]);
                }
                e0 = e1; e1 = e2; hv0 = hv1;
                #pragma unroll
                for (int jj = 0; jj < 8; jj++) hc[jj] = hn[jj];
            }
        }
    } else {
        // fallback: inline hid via LDS broadcast (Round-3 path)
        const float w10 = W1[lane];
        const float b1v = b1[lane];
        if (pb < pe) {
            int2 e0 = edge2[pb];
            float hv0 = h[(e0.x & 0xFFFF) * EMB + lane];
            for (int p = pb; p < pe; p++) {
                int pn = (p + 1 < pe) ? (p + 1) : (pe - 1);
                int2 e1 = edge2[pn];
                float hv1 = h[(e1.x & 0xFFFF) * EMB + lane];
                int r = (e0.x >> 16) & 7;
                float dist = __int_as_float(e0.y);
                float hid = fmaxf(fmaf(dist, w10, W1[(1 + r) * EMB + lane] + b1v), 0.0f);
                Prows[hw][41][lane] = hid;
                #pragma unroll
                for (int j = 0; j < 8; j++) {
                    float4 h4 = ((const float4*)&Prows[hw][41][0])[j];
                    P[4 * j + 0] = fmaf(h4.x, hv0, P[4 * j + 0]);
                    P[4 * j + 1] = fmaf(h4.y, hv0, P[4 * j + 1]);
                    P[4 * j + 2] = fmaf(h4.z, hv0, P[4 * j + 2]);
                    P[4 * j + 3] = fmaf(h4.w, hv0, P[4 * j + 3]);
                }
                atomicAdd(&Prows[hw][33 + r][lane], hv0);
                stot += hv0;
                e0 = e1; hv0 = hv1;
            }
        }
    }

    __threadfence_block();   // drain ds_add before readback (same-wave, cheap)

    // write reduction rows (pre-scaled)
    const float idg = invdeg[n];
    #pragma unroll
    for (int k = 0; k < 32; k++) Prows[hw][k][lane] = P[k] * idg;
    Prows[hw][32][lane] = stot * idg;
    #pragma unroll
    for (int r = 0; r < NREL; r++) {
        float v = Prows[hw][33 + r][lane];
        Prows[hw][33 + r][lane] = v * invcnt[n * NREL + r];
    }
    Prows[hw][41][lane] = h[n * EMB + lane];   // h_dst row
    __syncthreads();

    // ---------- contraction (lane = output column o, transposed W: 8x dwordx4) ----------
    float accN[NPB], accR[NPB];
    #pragma unroll
    for (int i = 0; i < NPB; i++) { accN[i] = 0.0f; accR[i] = 0.0f; }

    #pragma unroll 1
    for (int j = 0; j < 6; j++) {
        const int row = hw + 8 * j;
        if (row > 40) break;
        const float* Wsrc = (row < 33) ? (WTs + (size_t)row * 1024)
                                       : (WTl + (size_t)(row - 33) * 1024);
        const float4* Wp = (const float4*)(Wsrc + lane * 32);
        float4 w4[8];
        #pragma unroll
        for (int i = 0; i < 8; i++) w4[i] = Wp[i];
        const bool isN = (row <= 32);
        #pragma unroll
        for (int nd = 0; nd < NPB; nd++) {
            const float4* Pr = (const float4*)&Prows[nd][row][0];
            float acc = 0.0f;
            #pragma unroll
            for (int jj = 0; jj < 8; jj++) {
                float4 p4 = Pr[jj];                       // broadcast b128
                acc = fmaf(p4.x, w4[jj].x, acc);
                acc = fmaf(p4.y, w4[jj].y, acc);
                acc = fmaf(p4.z, w4[jj].z, acc);
                acc = fmaf(p4.w, w4[jj].w, acc);
            }
            if (isN) accN[nd] += acc; else accR[nd] += acc;
        }
    }

    // ---------- root terms (transposed roots; read h_dst row BEFORE Red aliasing) ----------
    float rootN = 0.0f, rootR = 0.0f;
    {
        const float4* hd4 = (const float4*)&Prows[hw][41][0];
        const float4* rT = (const float4*)(WTl + 8 * 1024 + lane * 32);   // rgcnRoot^T
        const float4* nT = (const float4*)(WTl + 9 * 1024 + lane * 32);   // nnRoot^T
        #pragma unroll
        for (int jj = 0; jj < 8; jj++) {
            float4 v = hd4[jj];
            float4 t = nT[jj];
            float4 u = rT[jj];
            rootN = fmaf(v.x, t.x, rootN); rootN = fmaf(v.y, t.y, rootN);
            rootN = fmaf(v.z, t.z, rootN); rootN = fmaf(v.w, t.w, rootN);
            rootR = fmaf(v.x, u.x, rootR); rootR = fmaf(v.y, u.y, rootR);
            rootR = fmaf(v.z, u.z, rootR); rootR = fmaf(v.w, u.w, rootR);
        }
    }
    const float hd_o = Prows[hw][41][lane];
    __syncthreads();

    // ---------- cross-half-wave reduction (alias Red over Prows) ----------
    float* Red = &Prows[0][0][0];                 // 4096 floats used
    #pragma unroll
    for (int nd = 0; nd < NPB; nd++) {
        Red[(hw * NPB + nd) * EMB + lane] = accN[nd];
        Red[2048 + (hw * NPB + nd) * EMB + lane] = accR[nd];
    }
    __syncthreads();

    float sn = 0.0f, sr = 0.0f;
    #pragma unroll
    for (int w = 0; w < NPB; w++) {
        sn += Red[(w * NPB + hw) * EMB + lane];
        sr += Red[2048 + (w * NPB + hw) * EMB + lane];
    }
    float o_r = fmaxf(sr + rootR + rgcnBias_l[lane], 0.0f);
    float o_n = fmaxf(sn + rootN + nnBias_l[lane], 0.0f);
    hout[n * EMB + lane] = hd_o + o_r + o_n;
}

// ---------------- launch ----------------

extern "C" void kernel_launch(void* const* d_in, const int* in_sizes, int n_in,
                              void* d_out, int out_size, void* d_ws, size_t ws_size,
                              hipStream_t stream) {
    const float* x        = (const float*)d_in[0];
    const int*   ei       = (const int*)d_in[1];
    const int*   et       = (const int*)d_in[2];
    const float* ed       = (const float*)d_in[3];
    const float* fcW      = (const float*)d_in[4];
    const float* fcb      = (const float*)d_in[5];
    const float* rgcnW    = (const float*)d_in[6];
    const float* rgcnRoot = (const float*)d_in[7];
    const float* rgcnBias = (const float*)d_in[8];
    const float* W1       = (const float*)d_in[9];
    const float* b1       = (const float*)d_in[10];
    const float* W2       = (const float*)d_in[11];
    const float* b2       = (const float*)d_in[12];
    const float* nnRoot   = (const float*)d_in[13];
    const float* nnBias   = (const float*)d_in[14];

    float* ws = (float*)d_ws;
    float* h_a    = ws;  ws += (size_t)N_NODES * EMB;
    float* h_b    = ws;  ws += (size_t)N_NODES * EMB;
    float* invdeg = ws;  ws += (size_t)N_NODES;
    float* invcnt = ws;  ws += (size_t)N_NODES * NREL;
    float* WT     = ws;  ws += (size_t)83 * 1024;
    int2* edge2   = (int2*)ws;     ws += (size_t)N_EDGES * 2;
    int* row_ptr  = (int*)ws;      ws += (size_t)(N_NODES + 1);
    int* deg      = (int*)ws;      ws += (size_t)N_NODES;       // deg..cursor contiguous
    int* relcnt   = (int*)ws;      ws += (size_t)N_NODES * NREL;
    int* cursor   = (int*)ws;      ws += (size_t)N_NODES;
    float* hidT   = ws;  ws += (size_t)N_EDGES * EMB;           // 51.2 MB, guarded
    (void)in_sizes; (void)n_in; (void)out_size;

    size_t need_bytes = (size_t)((float*)ws - (float*)d_ws) * 4;
    const int use_hid = (ws_size >= need_bytes) ? 1 : 0;

    zero_kernel<<<(10 * N_NODES + 255) / 256, 256, 0, stream>>>(deg, 10 * N_NODES);
    hist_kernel<<<(N_EDGES + 255) / 256, 256, 0, stream>>>(ei, et, deg, relcnt);
    scan_kernel<<<1, 1024, 0, stream>>>(deg, row_ptr);
    inv_kernel<<<(N_NODES + 255) / 256, 256, 0, stream>>>(deg, relcnt, invdeg, invcnt);
    scatter_kernel<<<(N_EDGES + 255) / 256, 256, 0, stream>>>(ei, et, ed, row_ptr,
                                                              cursor, edge2);
    wt_kernel<<<83, 256, 0, stream>>>(W2, b2, rgcnW, rgcnRoot, nnRoot, WT);
    if (use_hid)
        hid_kernel<<<(N_EDGES + 7) / 8, 256, 0, stream>>>(edge2, W1, b1, hidT);
    fc_kernel<<<N_NODES / 8, 256, 0, stream>>>(x, fcW, fcb, h_a);

    const float* hin = h_a;
    float* houtb = h_b;
    for (int l = 0; l < NLAYER; l++) {
        float* dst = (l == NLAYER - 1) ? (float*)d_out : houtb;
        layer_kernel<<<N_NODES / NPB, 256, 0, stream>>>(
            hin, edge2, row_ptr, invdeg, invcnt,
            use_hid ? hidT : nullptr, W1, b1,
            WT, WT + (size_t)(33 + l * 10) * 1024,
            rgcnBias + (size_t)l * EMB,
            nnBias + (size_t)l * EMB,
            use_hid, dst);
        float* old_in = (float*)hin;
        hin = dst;
        houtb = old_in;
    }
}

// Round 6
// 498.766 us; speedup vs baseline: 2.9948x; 2.9948x over previous
//
#include <hip/hip_runtime.h>

#define N_NODES 50000
#define N_EDGES 400000
#define EMB 32
#define NREL 8
#define NLAYER 5
#define NPB 16          // nodes per block (half-wave each, 512 threads)
#define KROWS 43        // 0..31 P, 32 Stot, 33..40 S_r, 41 h_dst(rgcnRoot), 42 h_dst(nnRoot)

typedef __attribute__((ext_vector_type(8))) short short8;   // 8 bf16 (4 VGPRs)
typedef __attribute__((ext_vector_type(4))) float f32x4;    // MFMA accumulator

__device__ __forceinline__ unsigned short f2bf(float f) {   // RNE f32 -> bf16
    unsigned u = __float_as_uint(f);
    unsigned r = u + 0x7FFF + ((u >> 16) & 1);
    return (unsigned short)(r >> 16);
}

// ---------------- setup kernels ----------------

__global__ __launch_bounds__(256) void zero_kernel(int* __restrict__ p, int n) {
    int i = blockIdx.x * 256 + threadIdx.x;
    if (i < n) p[i] = 0;
}

__global__ __launch_bounds__(256) void hist_kernel(const int* __restrict__ ei,
                                                   const int* __restrict__ et,
                                                   int* __restrict__ deg,
                                                   int* __restrict__ relcnt) {
    int e = blockIdx.x * 256 + threadIdx.x;
    if (e < N_EDGES) {
        int d = ei[N_EDGES + e];           // dst = edge_index[1]
        atomicAdd(&deg[d], 1);
        atomicAdd(&relcnt[d * NREL + et[e]], 1);
    }
}

__global__ __launch_bounds__(1024) void scan_kernel(const int* __restrict__ deg,
                                                    int* __restrict__ row_ptr) {
    __shared__ int wtot[16];
    __shared__ int pwt[16];
    __shared__ int carry_s;
    int tid = threadIdx.x;
    int lane = tid & 63;
    int w = tid >> 6;
    if (tid == 0) carry_s = 0;
    __syncthreads();
    for (int base = 0; base < N_NODES; base += 1024) {
        int i = base + tid;
        int v = (i < N_NODES) ? deg[i] : 0;
        int incl = v;
        #pragma unroll
        for (int off = 1; off < 64; off <<= 1) {
            int t = __shfl_up(incl, off, 64);
            if (lane >= off) incl += t;
        }
        if (lane == 63) wtot[w] = incl;
        __syncthreads();
        if (tid == 0) {
            int c = carry_s, run = 0;
            #pragma unroll
            for (int j = 0; j < 16; j++) { pwt[j] = c + run; run += wtot[j]; }
            carry_s = c + run;
        }
        __syncthreads();
        if (i < N_NODES) row_ptr[i] = pwt[w] + incl - v;
        __syncthreads();
    }
    if (tid == 0) row_ptr[N_NODES] = carry_s;
}

__global__ __launch_bounds__(256) void inv_kernel(const int* __restrict__ deg,
                                                  const int* __restrict__ relcnt,
                                                  float* __restrict__ invdeg,
                                                  float* __restrict__ invcnt) {
    int n = blockIdx.x * 256 + threadIdx.x;
    if (n < N_NODES) {
        int d = deg[n];
        invdeg[n] = 1.0f / (float)(d > 0 ? d : 1);
        #pragma unroll
        for (int r = 0; r < NREL; r++) {
            int c = relcnt[n * NREL + r];
            invcnt[n * NREL + r] = 1.0f / (float)(c > 0 ? c : 1);
        }
    }
}

__global__ __launch_bounds__(256) void scatter_kernel(const int* __restrict__ ei,
                                                      const int* __restrict__ et,
                                                      const float* __restrict__ ed,
                                                      const int* __restrict__ row_ptr,
                                                      int* __restrict__ cursor,
                                                      int2* __restrict__ edge2) {
    int e = blockIdx.x * 256 + threadIdx.x;
    if (e < N_EDGES) {
        int d = ei[N_EDGES + e];
        int pos = row_ptr[d] + atomicAdd(&cursor[d], 1);
        edge2[pos] = make_int2(ei[e] | (et[e] << 16), __float_as_int(ed[e]));
    }
}

// transpose+bf16 contraction weights: WB[m][o*32+i] = bf16(src_m[i*32+o])
// m 0..31: W2 rows; 32: b2; 33+l*10+j: j<8 rgcnW[l][j], j==8 rgcnRoot[l], j==9 nnRoot[l]
__global__ __launch_bounds__(256) void wtbf_kernel(const float* __restrict__ W2,
                                                   const float* __restrict__ b2,
                                                   const float* __restrict__ rgcnW,
                                                   const float* __restrict__ rgcnRoot,
                                                   const float* __restrict__ nnRoot,
                                                   unsigned short* __restrict__ WB) {
    int m = blockIdx.x;
    const float* src;
    if (m < 32) src = W2 + (size_t)m * 1024;
    else if (m == 32) src = b2;
    else {
        int t = m - 33, l = t / 10, j = t % 10;
        src = (j < 8) ? rgcnW + (size_t)(l * 8 + j) * 1024
            : (j == 8) ? rgcnRoot + (size_t)l * 1024
                       : nnRoot + (size_t)l * 1024;
    }
    unsigned short* dst = WB + (size_t)m * 1024;
    #pragma unroll
    for (int c = 0; c < 4; c++) {
        int idx = c * 256 + threadIdx.x;
        int o = idx >> 5, i = idx & 31;
        dst[o * 32 + i] = f2bf(src[i * 32 + o]);
    }
}

// ---------------- fc: h0 = relu(x @ fc_W + fc_b) ----------------

__global__ __launch_bounds__(256) void fc_kernel(const float* __restrict__ x,
                                                 const float* __restrict__ W,
                                                 const float* __restrict__ b,
                                                 float* __restrict__ h) {
    __shared__ __align__(16) float xt[8][EMB];
    int tid = threadIdx.x;
    int nl = tid >> 5, lane = tid & 31;
    int n0 = blockIdx.x * 8;
    xt[tid >> 5][tid & 31] = x[n0 * EMB + tid];
    __syncthreads();
    float acc = b[lane];
    #pragma unroll
    for (int i = 0; i < EMB; i++) acc += xt[nl][i] * W[i * EMB + lane];
    h[(n0 + nl) * EMB + lane] = fmaxf(acc, 0.0f);
}

// ---------------- fused layer kernel (edge phase fp32 + bf16 MFMA contraction) ----------------
// Edge phase (half-wave per node, lane = input feature i):
//   P[k][i] = sum_e hid_e[k]*h[src_e][i];  S_r[i] = sum_{e in rel r} h[src_e][i]
// LDS A-matrix rows (bf16, pre-scaled): 0..31 P*invdeg, 32 Stot*invdeg,
//   33..40 S_r*invcnt_r, 41 & 42 h_dst.
// Contraction: C[16,32] = A[16,43x32] x B[43x32,32] via mfma_f32_16x16x32_bf16.
//   Wave w handles K-rows rr = w+8j; rr<=32 or rr==42 -> accN, else -> accR.
// Cross-wave reduction: deterministic (no atomics) — each wave stores its full
//   zero-init partial tile to RedAll[w][1024] (overlaid on P_lds between
//   barriers), then 512 threads sum 8 partials each, stride-1 reads.
__global__ __launch_bounds__(512, 2) void layer_kernel(
    const float* __restrict__ h,
    const int2* __restrict__ edge2,
    const int* __restrict__ row_ptr,
    const float* __restrict__ invdeg,
    const float* __restrict__ invcnt,
    const float* __restrict__ W1,
    const float* __restrict__ b1,
    const unsigned short* __restrict__ WBs,   // rows 0..32 (W2^T, b2^T)
    const unsigned short* __restrict__ WBl,   // rows 33..42 (rgcnW^T x8, rgcnRoot^T, nnRoot^T)
    const float* __restrict__ rgcnBias_l,
    const float* __restrict__ nnBias_l,
    float* __restrict__ hout)
{
    __shared__ __align__(16) unsigned short P_lds[NPB][KROWS][EMB];  // 44032 B
    __shared__ __align__(16) float hidst[NPB][EMB];                  // 2048 B

    const int tid = threadIdx.x;
    const int hw = tid >> 5, lane = tid & 31;
    const int n0 = blockIdx.x * NPB;
    const int n = n0 + hw;                    // N divisible by 16: no guard

    // ---------- edge phase (fp32, registers) ----------
    float P[32], S[NREL];
    #pragma unroll
    for (int k = 0; k < 32; k++) P[k] = 0.0f;
    #pragma unroll
    for (int r = 0; r < NREL; r++) S[r] = 0.0f;

    const float w10 = W1[lane];
    const float b1v = b1[lane];

    const int pb = row_ptr[n], pe = row_ptr[n + 1];
    if (pb < pe) {
        int2 e0 = edge2[pb];
        float hv0 = h[(e0.x & 0xFFFF) * EMB + lane];
        for (int p = pb; p < pe; p++) {
            int pn = (p + 1 < pe) ? (p + 1) : (pe - 1);
            int2 e1 = edge2[pn];                              // prefetch
            float hv1 = h[(e1.x & 0xFFFF) * EMB + lane];      // prefetch gather
            int r = (e0.x >> 16) & 7;
            float dist = __int_as_float(e0.y);
            float hid = fmaxf(fmaf(dist, w10, W1[(1 + r) * EMB + lane] + b1v), 0.0f);
            hidst[hw][lane] = hid;            // half-wave broadcast (same wave, lockstep)
            #pragma unroll
            for (int j = 0; j < 8; j++) {
                float4 h4 = ((const float4*)&hidst[hw][0])[j];
                P[4 * j + 0] = fmaf(h4.x, hv0, P[4 * j + 0]);
                P[4 * j + 1] = fmaf(h4.y, hv0, P[4 * j + 1]);
                P[4 * j + 2] = fmaf(h4.z, hv0, P[4 * j + 2]);
                P[4 * j + 3] = fmaf(h4.w, hv0, P[4 * j + 3]);
            }
            #pragma unroll
            for (int rr = 0; rr < NREL; rr++)
                S[rr] += (r == rr) ? hv0 : 0.0f;
            e0 = e1; hv0 = hv1;
        }
    }

    // ---------- write bf16 A-rows (pre-scaled) ----------
    const float idg = invdeg[n];
    #pragma unroll
    for (int k = 0; k < 32; k++) P_lds[hw][k][lane] = f2bf(P[k] * idg);
    float stot = 0.0f;
    #pragma unroll
    for (int r = 0; r < NREL; r++) stot += S[r];
    P_lds[hw][32][lane] = f2bf(stot * idg);
    #pragma unroll
    for (int r = 0; r < NREL; r++)
        P_lds[hw][33 + r][lane] = f2bf(S[r] * invcnt[n * NREL + r]);
    unsigned short hdb = f2bf(h[n * EMB + lane]);
    P_lds[hw][41][lane] = hdb;                // h_dst for rgcnRoot K-step
    P_lds[hw][42][lane] = hdb;                // h_dst for nnRoot K-step
    __syncthreads();

    // ---------- MFMA contraction ----------
    const int wl = tid & 63;                  // wave lane
    const int w = tid >> 6;                   // wave id 0..7
    const int node16 = wl & 15;
    const int quad = wl >> 4;
    const int o0 = wl & 15;                   // B n-index (tile 0); tile 1 = +16

    f32x4 accN0 = {0.f, 0.f, 0.f, 0.f}, accN1 = {0.f, 0.f, 0.f, 0.f};
    f32x4 accR0 = {0.f, 0.f, 0.f, 0.f}, accR1 = {0.f, 0.f, 0.f, 0.f};

    #pragma unroll
    for (int j = 0; j < 6; j++) {
        const int rr = w + 8 * j;             // wave-uniform
        if (rr < KROWS) {
            const unsigned short* Bsrc = (rr < 33) ? (WBs + (size_t)rr * 1024)
                                                   : (WBl + (size_t)(rr - 33) * 1024);
            short8 bf0 = *(const short8*)(Bsrc + o0 * 32 + quad * 8);
            short8 bf1 = *(const short8*)(Bsrc + (o0 + 16) * 32 + quad * 8);
            short8 a = *(const short8*)&P_lds[node16][rr][quad * 8];
            if (rr <= 32 || rr == 42) {
                accN0 = __builtin_amdgcn_mfma_f32_16x16x32_bf16(a, bf0, accN0, 0, 0, 0);
                accN1 = __builtin_amdgcn_mfma_f32_16x16x32_bf16(a, bf1, accN1, 0, 0, 0);
            } else {
                accR0 = __builtin_amdgcn_mfma_f32_16x16x32_bf16(a, bf0, accR0, 0, 0, 0);
                accR1 = __builtin_amdgcn_mfma_f32_16x16x32_bf16(a, bf1, accR1, 0, 0, 0);
            }
        }
    }
    __syncthreads();                          // all A-reads done; safe to overlay RedAll

    // ---------- deterministic cross-wave reduction (no atomics) ----------
    // RedAll[w][0..511] = partial N tile, RedAll[w][512..1023] = partial R tile.
    // Every wave writes its FULL slice (accs were zero-init), so sums are exact.
    float* RedAll = (float*)&P_lds[0][0][0];  // 8 waves x 1024 floats = 32 KiB < 44 KiB
    {
        float* my = RedAll + w * 1024;
        #pragma unroll
        for (int reg = 0; reg < 4; reg++) {
            int nd = quad * 4 + reg;          // C/D: row(m=node)=quad*4+reg, col(n=o)=lane&15
            my[nd * 32 + o0]            = accN0[reg];
            my[nd * 32 + o0 + 16]       = accN1[reg];
            my[512 + nd * 32 + o0]      = accR0[reg];
            my[512 + nd * 32 + o0 + 16] = accR1[reg];
        }
    }
    __syncthreads();

    // ---------- epilogue (thread tid -> node tid>>5, output col tid&31) ----------
    {
        float sn = 0.0f, sr = 0.0f;
        #pragma unroll
        for (int ww = 0; ww < 8; ww++) {
            sn += RedAll[ww * 1024 + tid];          // stride-1, conflict-free
            sr += RedAll[ww * 1024 + 512 + tid];
        }
        int node = tid >> 5, o = tid & 31;
        float hd = h[(n0 + node) * EMB + o];        // coalesced: addr = n0*32 + tid
        float o_r = fmaxf(sr + rgcnBias_l[o], 0.0f);
        float o_n = fmaxf(sn + nnBias_l[o], 0.0f);
        hout[(n0 + node) * EMB + o] = hd + o_r + o_n;
    }
}

// ---------------- launch ----------------

extern "C" void kernel_launch(void* const* d_in, const int* in_sizes, int n_in,
                              void* d_out, int out_size, void* d_ws, size_t ws_size,
                              hipStream_t stream) {
    const float* x        = (const float*)d_in[0];
    const int*   ei       = (const int*)d_in[1];
    const int*   et       = (const int*)d_in[2];
    const float* ed       = (const float*)d_in[3];
    const float* fcW      = (const float*)d_in[4];
    const float* fcb      = (const float*)d_in[5];
    const float* rgcnW    = (const float*)d_in[6];
    const float* rgcnRoot = (const float*)d_in[7];
    const float* rgcnBias = (const float*)d_in[8];
    const float* W1       = (const float*)d_in[9];
    const float* b1       = (const float*)d_in[10];
    const float* W2       = (const float*)d_in[11];
    const float* b2       = (const float*)d_in[12];
    const float* nnRoot   = (const float*)d_in[13];
    const float* nnBias   = (const float*)d_in[14];

    float* ws = (float*)d_ws;
    float* h_a    = ws;  ws += (size_t)N_NODES * EMB;
    float* h_b    = ws;  ws += (size_t)N_NODES * EMB;
    float* invdeg = ws;  ws += (size_t)N_NODES;
    float* invcnt = ws;  ws += (size_t)N_NODES * NREL;
    unsigned short* WB = (unsigned short*)ws;  ws += (size_t)83 * 1024 / 2;  // 83 rows bf16
    int2* edge2   = (int2*)ws;     ws += (size_t)N_EDGES * 2;
    int* row_ptr  = (int*)ws;      ws += (size_t)(N_NODES + 1);
    int* deg      = (int*)ws;      ws += (size_t)N_NODES;       // deg..cursor contiguous
    int* relcnt   = (int*)ws;      ws += (size_t)N_NODES * NREL;
    int* cursor   = (int*)ws;      ws += (size_t)N_NODES;
    (void)in_sizes; (void)n_in; (void)out_size; (void)ws_size;

    zero_kernel<<<(10 * N_NODES + 255) / 256, 256, 0, stream>>>(deg, 10 * N_NODES);
    hist_kernel<<<(N_EDGES + 255) / 256, 256, 0, stream>>>(ei, et, deg, relcnt);
    scan_kernel<<<1, 1024, 0, stream>>>(deg, row_ptr);
    inv_kernel<<<(N_NODES + 255) / 256, 256, 0, stream>>>(deg, relcnt, invdeg, invcnt);
    scatter_kernel<<<(N_EDGES + 255) / 256, 256, 0, stream>>>(ei, et, ed, row_ptr,
                                                              cursor, edge2);
    wtbf_kernel<<<83, 256, 0, stream>>>(W2, b2, rgcnW, rgcnRoot, nnRoot, WB);
    fc_kernel<<<N_NODES / 8, 256, 0, stream>>>(x, fcW, fcb, h_a);

    const float* hin = h_a;
    float* houtb = h_b;
    for (int l = 0; l < NLAYER; l++) {
        float* dst = (l == NLAYER - 1) ? (float*)d_out : houtb;
        layer_kernel<<<N_NODES / NPB, 512, 0, stream>>>(
            hin, edge2, row_ptr, invdeg, invcnt, W1, b1,
            WB, WB + (size_t)(33 + l * 10) * 1024,
            rgcnBias + (size_t)l * EMB,
            nnBias + (size_t)l * EMB,
            dst);
        float* old_in = (float*)hin;
        hin = dst;
        houtb = old_in;
    }
}